// Round 1
// baseline (96.863 us; speedup 1.0000x reference)
//
#include <hip/hip_runtime.h>
#include <math.h>

namespace {
constexpr int B = 4, P = 64, V = 32, D = 256;
constexpr float MARGIN = 0.1f;
constexpr float L_REG = 0.1f, L_SIGMA = 0.05f;

// One wave (64 lanes) per (b, g, p). Lane = rotation r.
__global__ __launch_bounds__(256) void costs_kernel(
    const float* __restrict__ gt,    // (B,P,V,2)
    const float* __restrict__ pred,  // (B,P,V,2)
    const int*   __restrict__ mask,  // (B,P,V)
    const int*   __restrict__ cls,   // (B,P)
    float*       __restrict__ costs) // (B,P,P)
{
    const int wid  = blockIdx.x * 4 + (threadIdx.x >> 6);
    const int lane = threadIdx.x & 63;
    const int b    = wid >> 12;      // / (P*P) ; P*P = 4096
    const int rem  = wid & 4095;
    const int g    = rem >> 6;
    const int p    = rem & 63;

    // nv = count of mask==0 entries, via ballot over lanes 0..31
    const int mg = (lane < V) ? mask[(b * P + g) * V + lane] : 1;
    const int mp = (lane < V) ? mask[(b * P + p) * V + lane] : 1;
    const int nvg = __popcll(__ballot(mg == 0));
    const int nvp = __popcll(__ballot(mp == 0));
    const int mn  = (nvg < nvp) ? nvg : nvp;
    const bool is_poly = (cls[b * P + g] == 1);

    const float* gtg = gt   + (size_t)(b * P + g) * (V * 2);
    const float* prp = pred + (size_t)(b * P + p) * (V * 2);

    const int r = lane;
    const bool valid = is_poly ? (r < nvg) : (r < 2);
    float cost_r = INFINITY;
    if (valid && mn > 0) {
        float s = 0.0f;
        if (is_poly) {
            const int m = nvg;         // >= 1 here (r < nvg, r >= 0)
            int idx = r % m;           // (r + v) % nvg, incremental
            for (int v = 0; v < mn; ++v) {
                s += fabsf(gtg[2 * idx]     - prp[2 * v]) +
                     fabsf(gtg[2 * idx + 1] - prp[2 * v + 1]);
                ++idx; if (idx >= m) idx = 0;
            }
        } else {
            for (int v = 0; v < mn; ++v) {
                const int iv = r ? (V - 1 - v) : v;   // r==1: reversed over full V
                s += fabsf(gtg[2 * iv]     - prp[2 * v]) +
                     fabsf(gtg[2 * iv + 1] - prp[2 * v + 1]);
            }
        }
        cost_r = s / (2.0f * (float)mn);
    }
    // min-reduce across the 64-lane wave
    #pragma unroll
    for (int off = 32; off > 0; off >>= 1)
        cost_r = fminf(cost_r, __shfl_xor(cost_r, off));
    if (lane == 0) costs[wid] = cost_r;
}

// One block per batch b.
__global__ __launch_bounds__(256) void finish_kernel(
    const float* __restrict__ costs,  // (B,P,P)
    const float* __restrict__ mu,     // (B,P,D)
    const float* __restrict__ sigma,  // (B,P,D)
    float*       __restrict__ out)    // 5 * B
{
    const int b = blockIdx.x;
    const int t = threadIdx.x;

    __shared__ float sc[P * P];
    __shared__ float diag[P];
    __shared__ float rowmax[P], colmax[P];
    __shared__ float wreg[4], wsig[4];
    __shared__ int broken_s;

    const float* cb = costs + (size_t)b * P * P;
    for (int i = t; i < P * P; i += 256) sc[i] = cb[i];
    __syncthreads();
    if (t < P) diag[t] = sc[t * P + t];
    if (t == 0) broken_s = 0;
    __syncthreads();

    if (t < P) {
        // rowmax[g] = max_p!=g max(MARGIN - costs[g,p] + diag[g], 0); diag entry is 0
        const int g = t;
        const float dg = diag[g];
        float m = 0.0f;
        for (int p = 0; p < P; ++p) {
            if (p == g) continue;
            m = fmaxf(m, fmaxf(MARGIN - sc[g * P + p] + dg, 0.0f));
        }
        rowmax[g] = m;
    } else if (t < 2 * P) {
        const int p = t - P;
        const float dp = diag[p];
        float m = 0.0f;
        for (int g = 0; g < P; ++g) {
            if (g == p) continue;
            m = fmaxf(m, fmaxf(MARGIN - sc[g * P + p] + dp, 0.0f));
        }
        colmax[p] = m;
    } else if (t < 3 * P) {
        // broken: exists g!=p with costs[g,p] < diag[g] and costs[p,g] < diag[p]
        const int g = t - 2 * P;
        const float dg = diag[g];
        int br = 0;
        for (int p = 0; p < P; ++p) {
            if (p == g) continue;
            if (sc[g * P + p] < dg && sc[p * P + g] < diag[p]) { br = 1; break; }
        }
        if (br) atomicOr(&broken_s, 1);
    }

    // reg = sum(mu^2)/P ; sig = sum(1/sigma)/(P*D) — float4 vectorized
    float regs = 0.0f, sigs = 0.0f;
    const float4* mub = (const float4*)(mu    + (size_t)b * P * D);
    const float4* sgb = (const float4*)(sigma + (size_t)b * P * D);
    for (int i = t; i < P * D / 4; i += 256) {
        const float4 m4 = mub[i];
        regs += m4.x * m4.x + m4.y * m4.y + m4.z * m4.z + m4.w * m4.w;
        const float4 s4 = sgb[i];
        sigs += 1.0f / s4.x + 1.0f / s4.y + 1.0f / s4.z + 1.0f / s4.w;
    }
    #pragma unroll
    for (int off = 32; off > 0; off >>= 1) {
        regs += __shfl_xor(regs, off);
        sigs += __shfl_xor(sigs, off);
    }
    const int w = t >> 6;
    if ((t & 63) == 0) { wreg[w] = regs; wsig[w] = sigs; }
    __syncthreads();

    if (t == 0) {
        const float reg = (wreg[0] + wreg[1] + wreg[2] + wreg[3]) / (float)P;
        const float sig = (wsig[0] + wsig[1] + wsig[2] + wsig[3]) / (float)(P * D);
        float perm = 0.0f;
        for (int i = 0; i < P; ++i) perm += rowmax[i] + colmax[i];
        const float batch = L_REG * reg + L_SIGMA * sig + perm;
        out[0 * B + b] = batch;
        out[1 * B + b] = perm;
        out[2 * B + b] = reg;
        out[3 * B + b] = sig;
        out[4 * B + b] = broken_s ? 1.0f : 0.0f;
    }
}
} // namespace

extern "C" void kernel_launch(void* const* d_in, const int* in_sizes, int n_in,
                              void* d_out, int out_size, void* d_ws, size_t ws_size,
                              hipStream_t stream) {
    const float* gt    = (const float*)d_in[0];
    const float* pred  = (const float*)d_in[1];
    const float* mu    = (const float*)d_in[2];
    const float* sigma = (const float*)d_in[3];
    const int*   mask  = (const int*)d_in[4];
    const int*   cls   = (const int*)d_in[5];
    float* out   = (float*)d_out;
    float* costs = (float*)d_ws;   // B*P*P floats = 64 KiB

    costs_kernel<<<B * P * P / 4, 256, 0, stream>>>(gt, pred, mask, cls, costs);
    finish_kernel<<<B, 256, 0, stream>>>(costs, mu, sigma, out);
}